// Round 1
// baseline (228.485 us; speedup 1.0000x reference)
//
#include <hip/hip_runtime.h>

#define NDIM 4096
#define B_LG 256
#define B_SM 256
#define N_WID 128
#define R_LG 64
#define R_SM 16
#define BLOCK 512
#define MAXB 256           // bucket capacity per wid
#define MAXM 6             // max batches fused per item
#define PF 8               // float4 loads per software-pipeline group
#define OUT_SIZE (B_LG * R_LG + B_SM * R_SM)

// chunk geometry: uniform-ish item cost (128 KB / 64 KB of A per item)
#define DCH_LG 512                 // 8 chunks per large wid
#define DCH_SM 1024                // 4 chunks per small wid
#define NCH_LG (NDIM / DCH_LG)
#define NCH_SM (NDIM / DCH_SM)

typedef float floatv4 __attribute__((ext_vector_type(4)));  // nt-load-compatible

// ---- workspace layout (ints). Poisoned every iteration by the harness, so
//      setup_kernel initializes every word the main kernel reads. ----
#define WS_CNT_L  0
#define WS_CNT_S  128
#define WS_NWORK  256
#define WS_TICKET 260
#define WS_BKT_L  512
#define WS_BKT_S  (WS_BKT_L + N_WID * MAXB)
#define WS_WORK   (WS_BKT_S + N_WID * MAXB)   // item i at [WS_WORK+2i], [+2i+1]
#define MAX_WORK  4096

// ------------- kernel 1: bucket batches by wid + build worklist + zero out --
__global__ __launch_bounds__(BLOCK)
void setup_kernel(const int* __restrict__ wids_l,
                  const int* __restrict__ wids_s,
                  int* __restrict__ ws,
                  float* __restrict__ out)
{
    __shared__ int cl[N_WID], cs[N_WID];
    __shared__ int nwork;
    const int t = threadIdx.x;
    if (t < N_WID) { cl[t] = 0; cs[t] = 0; }
    if (t == 0) nwork = 0;
    __syncthreads();
    if (t < B_LG) {
        const int w = wids_l[t];
        const int s = atomicAdd(&cl[w], 1);
        ws[WS_BKT_L + w * MAXB + s] = t;
    } else if (t < B_LG + B_SM) {
        const int b = t - B_LG;
        const int w = wids_s[b];
        const int s = atomicAdd(&cs[w], 1);
        ws[WS_BKT_S + w * MAXB + s] = b;
    }
    __syncthreads();
    if (t < N_WID) {
        ws[WS_CNT_L + t] = cl[t];
        ws[WS_CNT_S + t] = cs[t];
        // emit compacted work items: (class, wid, chunk, group-start, M)
        int cnt = cl[t];
        for (int g = 0; g < cnt; g += MAXM) {
            const int Mi   = min(MAXM, cnt - g);
            const int base = atomicAdd(&nwork, NCH_LG);
            for (int c = 0; c < NCH_LG; ++c) {
                ws[WS_WORK + 2 * (base + c)]     = (t << 8) | c;          // large
                ws[WS_WORK + 2 * (base + c) + 1] = (g << 8) | Mi;
            }
        }
        cnt = cs[t];
        for (int g = 0; g < cnt; g += MAXM) {
            const int Mi   = min(MAXM, cnt - g);
            const int base = atomicAdd(&nwork, NCH_SM);
            for (int c = 0; c < NCH_SM; ++c) {
                ws[WS_WORK + 2 * (base + c)]     = (1 << 30) | (t << 8) | c; // small
                ws[WS_WORK + 2 * (base + c) + 1] = (g << 8) | Mi;
            }
        }
    }
    __syncthreads();
    if (t == 0) { ws[WS_NWORK] = nwork; ws[WS_TICKET] = 0; }
    for (int i = t; i < OUT_SIZE; i += BLOCK) out[i] = 0.0f;
}

// ------------- grouped chunk-GEMV work item, straight-line pipelined --------
// One 512-thread block streams a DCH-row chunk of A[wid] exactly once (non-
// temporal, fully unrolled so loads stay in flight across FMA groups) while
// accumulating M batches' partial dots. Chunks combine via atomicAdd into
// zero-initialized out.  NOTE: caller's loop barriers protect xs reuse — no
// leading __syncthreads here.
template<int R, int M, int DCH>
__device__ __forceinline__ void gemv_chunk(
    const float* __restrict__ x,      // x rows base for this class
    const float* __restrict__ Ab,     // A[wid]
    float* __restrict__ outb,         // out base for this class
    const int* __restrict__ batches,  // M batch indices (uniform scalar reads)
    int d0,                           // d offset of this chunk
    float* __restrict__ xs,           // LDS, >= M*DCH floats
    float* __restrict__ red)          // LDS [8][16][4]
{
    constexpr int LPR  = R / 4;         // lanes per A-row: 16 (R=64) or 4 (R=16)
    constexpr int ROWS = BLOCK / LPR;   // A-rows per float4-iter: 32 or 128
    constexpr int IT   = DCH / ROWS;    // 16 (large) or 8 (small)
    constexpr int NG   = IT / PF;       // 2 or 1 pipeline groups

    const int t = threadIdx.x;

    int rows[M];
#pragma unroll
    for (int m = 0; m < M; ++m) rows[m] = batches[m];  // uniform -> s_load

#pragma unroll
    for (int m = 0; m < M; ++m)
        for (int i = t; i < DCH / 4; i += BLOCK)
            reinterpret_cast<float4*>(xs + m * DCH)[i] =
                reinterpret_cast<const float4*>(x + (size_t)rows[m] * NDIM + d0)[i];
    __syncthreads();

    const int d_sub  = t / LPR;
    const int r_base = (t % LPR) * 4;
    const float* Abt = Ab + ((size_t)d0 + d_sub) * R + r_base;

    float acc[M][4];
#pragma unroll
    for (int m = 0; m < M; ++m)
#pragma unroll
        for (int j = 0; j < 4; ++j) acc[m][j] = 0.0f;

    // Fully unrolled: NG groups of PF nontemporal float4 loads + FMAs in one
    // straight-line block; scheduler overlaps group g+1 loads with group g
    // FMAs (fine-grained vmcnt, no full drains).
#pragma unroll
    for (int g = 0; g < NG; ++g) {
        floatv4 buf[PF];
#pragma unroll
        for (int p = 0; p < PF; ++p)
            buf[p] = __builtin_nontemporal_load(
                reinterpret_cast<const floatv4*>(Abt + (size_t)(g * PF + p) * ROWS * R));
#pragma unroll
        for (int p = 0; p < PF; ++p) {
            const int d = (g * PF + p) * ROWS + d_sub;
#pragma unroll
            for (int m = 0; m < M; ++m) {
                const float xv = xs[m * DCH + d];
                acc[m][0] = fmaf(xv, buf[p].x, acc[m][0]);
                acc[m][1] = fmaf(xv, buf[p].y, acc[m][1]);
                acc[m][2] = fmaf(xv, buf[p].z, acc[m][2]);
                acc[m][3] = fmaf(xv, buf[p].w, acc[m][3]);
            }
        }
    }

    // reduce: shuffle within wave, LDS across 8 waves, atomicAdd per chunk
    const int wave = t >> 6;
    const int lane = t & 63;
#pragma unroll
    for (int m = 0; m < M; ++m)
#pragma unroll
        for (int off = 32; off >= LPR; off >>= 1)
#pragma unroll
            for (int j = 0; j < 4; ++j)
                acc[m][j] += __shfl_down(acc[m][j], off, 64);

#pragma unroll
    for (int m = 0; m < M; ++m) {
        __syncthreads();
        if (lane < LPR)
#pragma unroll
            for (int j = 0; j < 4; ++j) red[(wave * 16 + lane) * 4 + j] = acc[m][j];
        __syncthreads();
        if (t < R) {
            const int rl = t / 4, j = t % 4;
            float v = 0.0f;
#pragma unroll
            for (int w = 0; w < 8; ++w) v += red[(w * 16 + rl) * 4 + j];
            atomicAdd(outb + (size_t)rows[m] * R + t, v);
        }
    }
}

// ------------- kernel 2: persistent blocks + dynamic work queue -------------
// Blocks pull (class, wid, chunk, group) items off a global atomic ticket.
// Removes the static-map tail: empty wids cost nothing, no round quantization,
// large/small interleave freely. Items are ~uniform bytes (128 KB / 64 KB) so
// HBM stays saturated until the queue drains.
__global__ __launch_bounds__(BLOCK, 4)
void SequentialLoraA_kernel(const float* __restrict__ x,
                            const float* __restrict__ Al,
                            const float* __restrict__ As,
                            float* __restrict__ out,
                            int* __restrict__ ws)
{
    __shared__ float xs[MAXM * DCH_SM];  // 24 KB (worst case: small, M=6)
    __shared__ float red[8 * 16 * 4];    // 2 KB
    __shared__ int s_item;

    const int t  = threadIdx.x;
    const int nw = ws[WS_NWORK];

    for (;;) {
        __syncthreads();   // (a) previous item's xs/red reads done; s_item free
        if (t == 0) s_item = atomicAdd(ws + WS_TICKET, 1);
        __syncthreads();   // (b) s_item visible
        const int it = s_item;
        if (it >= nw) return;

        const int a   = ws[WS_WORK + 2 * it];
        const int b   = ws[WS_WORK + 2 * it + 1];
        const int wid = (a >> 8) & 0x7f;
        const int Mi  = b & 0xff;
        const int gs  = b >> 8;

        if (a & (1 << 30)) {  // small class
            const int d0 = (a & 0xff) * DCH_SM;
            const float* xb  = x + (size_t)B_LG * NDIM;
            const float* Ab  = As + (size_t)wid * NDIM * R_SM;
            float*       ob  = out + (size_t)B_LG * R_LG;
            const int*   bkt = ws + WS_BKT_S + wid * MAXB + gs;
            switch (Mi) {
              case 1: gemv_chunk<R_SM, 1, DCH_SM>(xb, Ab, ob, bkt, d0, xs, red); break;
              case 2: gemv_chunk<R_SM, 2, DCH_SM>(xb, Ab, ob, bkt, d0, xs, red); break;
              case 3: gemv_chunk<R_SM, 3, DCH_SM>(xb, Ab, ob, bkt, d0, xs, red); break;
              case 4: gemv_chunk<R_SM, 4, DCH_SM>(xb, Ab, ob, bkt, d0, xs, red); break;
              case 5: gemv_chunk<R_SM, 5, DCH_SM>(xb, Ab, ob, bkt, d0, xs, red); break;
              default: gemv_chunk<R_SM, 6, DCH_SM>(xb, Ab, ob, bkt, d0, xs, red); break;
            }
        } else {              // large class
            const int d0 = (a & 0xff) * DCH_LG;
            const float* Ab  = Al + (size_t)wid * NDIM * R_LG;
            const int*   bkt = ws + WS_BKT_L + wid * MAXB + gs;
            switch (Mi) {
              case 1: gemv_chunk<R_LG, 1, DCH_LG>(x, Ab, out, bkt, d0, xs, red); break;
              case 2: gemv_chunk<R_LG, 2, DCH_LG>(x, Ab, out, bkt, d0, xs, red); break;
              case 3: gemv_chunk<R_LG, 3, DCH_LG>(x, Ab, out, bkt, d0, xs, red); break;
              case 4: gemv_chunk<R_LG, 4, DCH_LG>(x, Ab, out, bkt, d0, xs, red); break;
              case 5: gemv_chunk<R_LG, 5, DCH_LG>(x, Ab, out, bkt, d0, xs, red); break;
              default: gemv_chunk<R_LG, 6, DCH_LG>(x, Ab, out, bkt, d0, xs, red); break;
            }
        }
    }
}

extern "C" void kernel_launch(void* const* d_in, const int* in_sizes, int n_in,
                              void* d_out, int out_size, void* d_ws, size_t ws_size,
                              hipStream_t stream) {
    const float* x      = (const float*)d_in[0];
    const int*   wids_l = (const int*)d_in[1];
    const int*   wids_s = (const int*)d_in[2];
    const float* Al     = (const float*)d_in[3];
    const float* As     = (const float*)d_in[4];
    float* out = (float*)d_out;
    int*   ws  = (int*)d_ws;

    setup_kernel<<<1, BLOCK, 0, stream>>>(wids_l, wids_s, ws, out);
    // 1024 blocks: over-provisioned vs ~2 resident/CU; extra blocks find the
    // queue empty and exit — dynamic ticket makes over-provisioning safe.
    SequentialLoraA_kernel<<<1024, BLOCK, 0, stream>>>(x, Al, As, out, ws);
}

// Round 3
// 216.529 us; speedup vs baseline: 1.0552x; 1.0552x over previous
//
#include <hip/hip_runtime.h>

#define NDIM 4096
#define B_LG 256
#define B_SM 256
#define N_WID 128
#define R_LG 64
#define R_SM 16
#define BLOCK 512
#define MAXB 256           // bucket capacity per wid
#define MAXM 6             // max batches fused per item
#define PF 8               // float4 loads per software-pipeline group
#define OUT_SIZE (B_LG * R_LG + B_SM * R_SM)

// One block owns one (wid, batch-group) over a d-range and accumulates across
// chunks in registers. Large groups split into 2 d-halves (512 KB of A each);
// small groups unsplit (256 KB). ~360 items < 512 resident slots -> single
// round, no tail, no ticket. Reduce + atomicAdd once per BLOCK, not per chunk.
#define DCH_LG 512                 // chunk rows, large (ROWS=32, IT=16, NG=2)
#define NCH_LG 4                   // chunks per half (covers 2048 of d)
#define DCH_SM 1024                // chunk rows, small (ROWS=128, IT=8, NG=1)
#define NCH_SM 4                   // chunks (covers all 4096 of d)
#define GRID_MAIN 512              // >= worst-case items (<=384)

typedef float floatv4 __attribute__((ext_vector_type(4)));  // nt-load-compatible

// ---- workspace layout (ints). Poisoned every iteration by the harness, so
//      setup_kernel initializes every word the main kernel reads. ----
#define WS_NWORK  0
#define WS_BKT_L  256
#define WS_BKT_S  (WS_BKT_L + N_WID * MAXB)
#define WS_WORK   (WS_BKT_S + N_WID * MAXB)   // item i at [WS_WORK+2i], [+2i+1]

// ------------- kernel 1: bucket batches by wid + build worklist + zero out --
__global__ __launch_bounds__(BLOCK)
void setup_kernel(const int* __restrict__ wids_l,
                  const int* __restrict__ wids_s,
                  int* __restrict__ ws,
                  float* __restrict__ out)
{
    __shared__ int cl[N_WID], cs[N_WID];
    __shared__ int nwork;
    const int t = threadIdx.x;
    if (t < N_WID) { cl[t] = 0; cs[t] = 0; }
    if (t == 0) nwork = 0;
    __syncthreads();
    if (t < B_LG) {
        const int w = wids_l[t];
        const int s = atomicAdd(&cl[w], 1);
        ws[WS_BKT_L + w * MAXB + s] = t;
    } else if (t < B_LG + B_SM) {
        const int b = t - B_LG;
        const int w = wids_s[b];
        const int s = atomicAdd(&cs[w], 1);
        ws[WS_BKT_S + w * MAXB + s] = b;
    }
    __syncthreads();
    if (t < N_WID) {
        // emit work items: (class, wid, d-half, group-start, M)
        int cnt = cl[t];
        for (int g = 0; g < cnt; g += MAXM) {
            const int Mi   = min(MAXM, cnt - g);
            const int base = atomicAdd(&nwork, 2);
            for (int h = 0; h < 2; ++h) {               // large: 2 d-halves
                ws[WS_WORK + 2 * (base + h)]     = (t << 8) | h;
                ws[WS_WORK + 2 * (base + h) + 1] = (g << 8) | Mi;
            }
        }
        cnt = cs[t];
        for (int g = 0; g < cnt; g += MAXM) {
            const int Mi   = min(MAXM, cnt - g);
            const int base = atomicAdd(&nwork, 1);      // small: one item
            ws[WS_WORK + 2 * base]     = (1 << 30) | (t << 8);
            ws[WS_WORK + 2 * base + 1] = (g << 8) | Mi;
        }
    }
    __syncthreads();
    if (t == 0) ws[WS_NWORK] = nwork;
    for (int i = t; i < OUT_SIZE; i += BLOCK) out[i] = 0.0f;
}

// ------------- one (wid, group, d-range) item: register-resident accum ------
// Streams NCH chunks of A[wid] exactly once (non-temporal, straight-line
// unrolled so loads stay in flight across FMA groups), accumulating M batches'
// partials in registers ACROSS chunks. One reduce + one atomicAdd per block.
template<int R, int M, int DCH, int NCH>
__device__ __forceinline__ void gemv_item(
    const float* __restrict__ x,      // x rows base for this class
    const float* __restrict__ Ab,     // A[wid]
    float* __restrict__ outb,         // out base for this class
    const int* __restrict__ batches,  // M batch indices (uniform reads)
    int dbase,                        // d offset of this item's range
    float* __restrict__ xs,           // LDS, >= M*DCH floats
    float* __restrict__ red)          // LDS [8][16][4]
{
    constexpr int LPR  = R / 4;         // lanes per A-row: 16 (R=64) or 4 (R=16)
    constexpr int ROWS = BLOCK / LPR;   // A-rows per float4-iter: 32 or 128
    constexpr int IT   = DCH / ROWS;    // 16 (large) or 8 (small)
    constexpr int NG   = IT / PF;       // 2 or 1 pipeline groups
    static_assert(IT % PF == 0, "chunk not divisible by pipeline group");

    const int t = threadIdx.x;

    int rows[M];
#pragma unroll
    for (int m = 0; m < M; ++m) rows[m] = batches[m];

    const int d_sub  = t / LPR;
    const int r_base = (t % LPR) * 4;

    float acc[M][4];
#pragma unroll
    for (int m = 0; m < M; ++m)
#pragma unroll
        for (int j = 0; j < 4; ++j) acc[m][j] = 0.0f;

    for (int c = 0; c < NCH; ++c) {
        const int d0 = dbase + c * DCH;

        __syncthreads();  // previous chunk's xs reads finished
#pragma unroll
        for (int m = 0; m < M; ++m)
            for (int i = t; i < DCH / 4; i += BLOCK)
                reinterpret_cast<float4*>(xs + m * DCH)[i] =
                    reinterpret_cast<const float4*>(x + (size_t)rows[m] * NDIM + d0)[i];
        __syncthreads();

        const float* Abt = Ab + ((size_t)d0 + d_sub) * R + r_base;

        // NG groups of PF nontemporal float4 loads + FMAs, straight-line so
        // the scheduler overlaps group g+1 loads with group g FMAs.
#pragma unroll
        for (int g = 0; g < NG; ++g) {
            floatv4 buf[PF];
#pragma unroll
            for (int p = 0; p < PF; ++p)
                buf[p] = __builtin_nontemporal_load(
                    reinterpret_cast<const floatv4*>(Abt + (size_t)(g * PF + p) * ROWS * R));
#pragma unroll
            for (int p = 0; p < PF; ++p) {
                const int d = (g * PF + p) * ROWS + d_sub;
#pragma unroll
                for (int m = 0; m < M; ++m) {
                    const float xv = xs[m * DCH + d];
                    acc[m][0] = fmaf(xv, buf[p].x, acc[m][0]);
                    acc[m][1] = fmaf(xv, buf[p].y, acc[m][1]);
                    acc[m][2] = fmaf(xv, buf[p].z, acc[m][2]);
                    acc[m][3] = fmaf(xv, buf[p].w, acc[m][3]);
                }
            }
        }
    }

    // reduce ONCE per block: shuffle within wave, LDS across 8 waves, atomicAdd
    const int wave = t >> 6;
    const int lane = t & 63;
#pragma unroll
    for (int m = 0; m < M; ++m)
#pragma unroll
        for (int off = 32; off >= LPR; off >>= 1)
#pragma unroll
            for (int j = 0; j < 4; ++j)
                acc[m][j] += __shfl_down(acc[m][j], off, 64);

#pragma unroll
    for (int m = 0; m < M; ++m) {
        __syncthreads();
        if (lane < LPR)
#pragma unroll
            for (int j = 0; j < 4; ++j) red[(wave * 16 + lane) * 4 + j] = acc[m][j];
        __syncthreads();
        if (t < R) {
            const int rl = t / 4, j = t % 4;
            float v = 0.0f;
#pragma unroll
            for (int w = 0; w < 8; ++w) v += red[(w * 16 + rl) * 4 + j];
            atomicAdd(outb + (size_t)rows[m] * R + t, v);
        }
    }
}

// ------------- kernel 2: static item map, one block per item ----------------
// ~360 expected items (<=384 worst case) all resident at 2 blocks/CU -> single
// scheduling round; blocks past nwork exit immediately.
__global__ __launch_bounds__(BLOCK, 4)
void SequentialLoraA_kernel(const float* __restrict__ x,
                            const float* __restrict__ Al,
                            const float* __restrict__ As,
                            float* __restrict__ out,
                            const int* __restrict__ ws)
{
    __shared__ float xs[MAXM * DCH_SM];  // 24 KB
    __shared__ float red[8 * 16 * 4];    // 2 KB

    const int it = blockIdx.x;
    if (it >= ws[WS_NWORK]) return;

    const int a   = ws[WS_WORK + 2 * it];
    const int b   = ws[WS_WORK + 2 * it + 1];
    const int wid = (a >> 8) & 0x7f;
    const int Mi  = b & 0xff;
    const int gs  = b >> 8;

    if (a & (1 << 30)) {  // small class: full d-range, 4 chunks of 1024
        const float* xb  = x + (size_t)B_LG * NDIM;
        const float* Ab  = As + (size_t)wid * NDIM * R_SM;
        float*       ob  = out + (size_t)B_LG * R_LG;
        const int*   bkt = ws + WS_BKT_S + wid * MAXB + gs;
        switch (Mi) {
          case 1:  gemv_item<R_SM, 1, DCH_SM, NCH_SM>(xb, Ab, ob, bkt, 0, xs, red); break;
          case 2:  gemv_item<R_SM, 2, DCH_SM, NCH_SM>(xb, Ab, ob, bkt, 0, xs, red); break;
          case 3:  gemv_item<R_SM, 3, DCH_SM, NCH_SM>(xb, Ab, ob, bkt, 0, xs, red); break;
          case 4:  gemv_item<R_SM, 4, DCH_SM, NCH_SM>(xb, Ab, ob, bkt, 0, xs, red); break;
          case 5:  gemv_item<R_SM, 5, DCH_SM, NCH_SM>(xb, Ab, ob, bkt, 0, xs, red); break;
          default: gemv_item<R_SM, 6, DCH_SM, NCH_SM>(xb, Ab, ob, bkt, 0, xs, red); break;
        }
    } else {              // large class: d-half, 4 chunks of 512
        const int dbase = (a & 1) * (NCH_LG * DCH_LG);
        const float* Ab  = Al + (size_t)wid * NDIM * R_LG;
        const int*   bkt = ws + WS_BKT_L + wid * MAXB + gs;
        switch (Mi) {
          case 1:  gemv_item<R_LG, 1, DCH_LG, NCH_LG>(x, Ab, out, bkt, dbase, xs, red); break;
          case 2:  gemv_item<R_LG, 2, DCH_LG, NCH_LG>(x, Ab, out, bkt, dbase, xs, red); break;
          case 3:  gemv_item<R_LG, 3, DCH_LG, NCH_LG>(x, Ab, out, bkt, dbase, xs, red); break;
          case 4:  gemv_item<R_LG, 4, DCH_LG, NCH_LG>(x, Ab, out, bkt, dbase, xs, red); break;
          case 5:  gemv_item<R_LG, 5, DCH_LG, NCH_LG>(x, Ab, out, bkt, dbase, xs, red); break;
          default: gemv_item<R_LG, 6, DCH_LG, NCH_LG>(x, Ab, out, bkt, dbase, xs, red); break;
        }
    }
}

extern "C" void kernel_launch(void* const* d_in, const int* in_sizes, int n_in,
                              void* d_out, int out_size, void* d_ws, size_t ws_size,
                              hipStream_t stream) {
    const float* x      = (const float*)d_in[0];
    const int*   wids_l = (const int*)d_in[1];
    const int*   wids_s = (const int*)d_in[2];
    const float* Al     = (const float*)d_in[3];
    const float* As     = (const float*)d_in[4];
    float* out = (float*)d_out;
    int*   ws  = (int*)d_ws;

    setup_kernel<<<1, BLOCK, 0, stream>>>(wids_l, wids_s, ws, out);
    SequentialLoraA_kernel<<<GRID_MAIN, BLOCK, 0, stream>>>(x, Al, As, out, ws);
}